// Round 25
// baseline (235.609 us; speedup 1.0000x reference)
//
#include <hip/hip_runtime.h>

#define E_TOTAL 50000
#define NTILES  3125      // E_TOTAL / 16, exact

// ---- workspace map (bytes) ----
#define OFF_WSB 458752ull
#define OFF_Q   524288ull
#define OFF_EK  (OFF_Q  + 12800000ull)
#define OFF_EM  (OFF_EK + 12800000ull)
#define OFF_SK  (OFF_EM + 12800000ull)   // 3 bufs, stride 12.8MB
#define OFF_SM  (OFF_SK + 38400000ull)   // 3 bufs, stride 12.8MB
#define WS_NEED (OFF_SM + 38400000ull)   // 115,724,288 B

typedef float f4  __attribute__((ext_vector_type(4)));
typedef short s8v __attribute__((ext_vector_type(8)));
typedef short s4v __attribute__((ext_vector_type(4)));

typedef __attribute__((address_space(3))) unsigned lds_u32;
typedef __attribute__((address_space(1))) const unsigned g_u32;

__device__ __forceinline__ short f2bf(float x){
  unsigned u = __builtin_bit_cast(unsigned, x);
  u += 0x7fffu + ((u >> 16) & 1u);
  return (short)(u >> 16);
}
__device__ __forceinline__ float bf2f(short s){
  unsigned u = ((unsigned)(unsigned short)s) << 16;
  return __builtin_bit_cast(float, u);
}
__device__ __forceinline__ float sigm(float x){ return 1.f/(1.f + __expf(-x)); }

__device__ __forceinline__ s8v load_bfrag(const float* p){
  f4 a = *(const f4*)p;
  f4 b = *(const f4*)(p + 4);
  s8v r;
  r[0]=f2bf(a[0]); r[1]=f2bf(a[1]); r[2]=f2bf(a[2]); r[3]=f2bf(a[3]);
  r[4]=f2bf(b[0]); r[5]=f2bf(b[1]); r[6]=f2bf(b[2]); r[7]=f2bf(b[3]);
  return r;
}

// Unfenced GEMM (fused fallback only).
__device__ __forceinline__ void mm8l(f4* acc, const s8v* B, const s8v* A, int lane){
  #pragma unroll
  for (int mb = 0; mb < 8; ++mb){
    #pragma unroll
    for (int kk = 0; kk < 4; ++kk){
      s8v af = A[(mb*4 + kk)*64 + lane];
      acc[mb] = __builtin_amdgcn_mfma_f32_16x16x32_bf16(af, B[kk], acc[mb], 0, 0, 0);
    }
  }
}

// FENCED GEMM: sched_barrier every 2 mb-blocks caps in-flight LDS A-reads
// (prevents whole-matrix hoist -> spills; proven clean r14-r24; r22 proved
// the unfenced form spills 58MB of scratch in grid-stride loops).
__device__ __forceinline__ void mm8f(f4* acc, const s8v* B, const s8v* A, int lane){
  #pragma unroll
  for (int mb = 0; mb < 8; mb += 2){
    #pragma unroll
    for (int m2 = 0; m2 < 2; ++m2){
      #pragma unroll
      for (int kk = 0; kk < 4; ++kk){
        s8v af = A[((mb+m2)*4 + kk)*64 + lane];
        acc[mb+m2] = __builtin_amdgcn_mfma_f32_16x16x32_bf16(af, B[kk], acc[mb+m2], 0, 0, 0);
      }
    }
    __builtin_amdgcn_sched_barrier(0);
  }
}

// 32KB matrix stage, 256-thread block (8 x 16B per thread)
__device__ __forceinline__ void stage_mat(const short* __restrict__ src,
                                          short* dst, int wid, int lane){
  #pragma unroll
  for (int j = 0; j < 8; ++j){
    const short* gsrc = src + j*2048 + wid*512 + lane*8;
    short* ldst = dst + j*2048 + wid*512;
    __builtin_amdgcn_global_load_lds((g_u32*)(const void*)gsrc, (lds_u32*)(void*)ldst, 16, 0, 0);
  }
}
// 32KB matrix stage, 512-thread block (4 x 16B per thread)
__device__ __forceinline__ void stage_mat512(const short* __restrict__ src,
                                             short* dst, int wid, int lane){
  #pragma unroll
  for (int j = 0; j < 4; ++j){
    const short* gsrc = src + j*4096 + wid*512 + lane*8;
    short* ldst = dst + j*4096 + wid*512;
    __builtin_amdgcn_global_load_lds((g_u32*)(const void*)gsrc, (lds_u32*)(void*)ldst, 16, 0, 0);
  }
}

__device__ __forceinline__ s8v pack_pair(const f4& a0, const f4& a1){
  s8v o;
  #pragma unroll
  for (int p = 0; p < 4; ++p){ o[p] = f2bf(a0[p]); o[4+p] = f2bf(a1[p]); }
  return o;
}

// ---------------------------------------------------------------------------
// pack_weights / make_biases (unchanged)
// ---------------------------------------------------------------------------
__global__ __launch_bounds__(256) void pack_weights(
    const float* __restrict__ Wq, const float* __restrict__ Wk, const float* __restrict__ Wv,
    const float* __restrict__ Wke, const float* __restrict__ Wve, const float* __restrict__ We,
    const float* __restrict__ Wc, const float* __restrict__ Wk1, const float* __restrict__ Wk2,
    const float* __restrict__ Wm1, const float* __restrict__ Wm2,
    short* __restrict__ wsm)
{
  int mi   = blockIdx.x >> 6;
  int elem = ((blockIdx.x & 63) << 8) + threadIdx.x;
  int p  = elem & 7;
  int l  = (elem >> 3) & 63;
  int kk = (elem >> 9) & 3;
  int mb = elem >> 11;
  int gg = l >> 4;
  int m  = mb*16 + (l & 15);
  bool dlay = (mi == 5) || (mi == 6) || (mi == 7);
  int k = dlay ? (kk*32 + ((p < 4) ? (gg*4 + p) : (16 + gg*4 + (p - 4))))
               : (kk*32 + gg*8 + p);

  const float* X = nullptr; const float* Y = nullptr; const float* W = nullptr;
  switch (mi){
    case 0: W = Wq; break;
    case 1: X = Wk; Y = Wk1;            break;
    case 2: X = Wv; Y = Wm1;            break;
    case 3: X = We; Y = Wk1 + 256*128;  break;
    case 4: X = We; Y = Wm1 + 256*128;  break;
    case 5: W = Wk2; break;
    case 6: W = Wm2; break;
    case 7: W = Wc;  break;
    default:
      if (mi < 11){ X = Wke + (mi-8)*16384;  Y = Wk1 + 128*128; }
      else        { X = Wve + (mi-11)*16384; Y = Wm1 + 128*128; }
  }
  float v;
  if (W){
    v = W[k*128 + m];
  } else {
    v = 0.f;
    for (int j = 0; j < 128; ++j) v += X[k*128 + j] * Y[j*128 + m];
  }
  wsm[(size_t)mi*16384 + elem] = f2bf(v);
}

__global__ __launch_bounds__(128) void make_biases(
    const float* __restrict__ bk,  const float* __restrict__ bke, const float* __restrict__ bk1,
    const float* __restrict__ bv,  const float* __restrict__ bve, const float* __restrict__ bm1,
    const float* __restrict__ Wk1, const float* __restrict__ Wm1,
    float* __restrict__ wsb)
{
  int b = blockIdx.x;
  int t = b % 3;
  bool isM = b >= 3;
  int o = threadIdx.x;
  const float* W  = isM ? Wm1 : Wk1;
  const float* b0 = isM ? bv  : bk;
  const float* be = (isM ? bve : bke) + t*128;
  const float* b1 = isM ? bm1 : bk1;
  float v = b1[o];
  for (int j = 0; j < 128; ++j)
    v += b0[j]*W[j*128 + o] + be[j]*W[(128 + j)*128 + o];
  wsb[b*128 + o] = v;
}

// ---------------------------------------------------------------------------
// proj (512 threads = 8 waves, launch_bounds(512,1)): q^/ek/em bf16 pair-
// layout. {Wq,GK,GM} persistent (96KB -> 1 block/CU, now 8 waves resident).
// ---------------------------------------------------------------------------
__global__ __launch_bounds__(512, 1) void proj(
    const float* __restrict__ edge, const float* __restrict__ bq,
    const short* __restrict__ wsm, char* __restrict__ ws)
{
  __shared__ short lds[3*16384];
  const int lane = threadIdx.x & 63;
  const int wid  = threadIdx.x >> 6;     // 0..7
  stage_mat512(wsm + 0*16384, lds,          wid, lane);
  stage_mat512(wsm + 1*16384, lds + 16384,  wid, lane);
  stage_mat512(wsm + 2*16384, lds + 32768,  wid, lane);
  __syncthreads();
  const int g = lane >> 4, er = lane & 15;
  short* wq  = (short*)(ws + OFF_Q);
  short* wek = (short*)(ws + OFF_EK);
  short* wem = (short*)(ws + OFF_EM);

  #pragma unroll 1
  for (int tile = blockIdx.x*8 + wid; tile < NTILES; tile += 2048){
    const float* erow = edge + ((size_t)tile*16 + er)*128;
    s8v BE[4];
    #pragma unroll
    for (int kk = 0; kk < 4; ++kk) BE[kk] = load_bfrag(erow + kk*32 + g*8);

    f4 acc[8];
    #pragma unroll
    for (int mb = 0; mb < 8; ++mb) acc[mb] = *(const f4*)(bq + mb*16 + g*4);
    mm8f(acc, BE, (const s8v*)lds, lane);
    #pragma unroll
    for (int c = 0; c < 4; ++c)
      *(s8v*)(wq + (size_t)tile*2048 + c*512 + lane*8) = pack_pair(acc[2*c], acc[2*c+1]);

    #pragma unroll
    for (int mb = 0; mb < 8; ++mb){ f4 z = {0.f,0.f,0.f,0.f}; acc[mb] = z; }
    mm8f(acc, BE, (const s8v*)(lds + 16384), lane);
    #pragma unroll
    for (int c = 0; c < 4; ++c)
      *(s8v*)(wek + (size_t)tile*2048 + c*512 + lane*8) = pack_pair(acc[2*c], acc[2*c+1]);

    #pragma unroll
    for (int mb = 0; mb < 8; ++mb){ f4 z = {0.f,0.f,0.f,0.f}; acc[mb] = z; }
    mm8f(acc, BE, (const s8v*)(lds + 32768), lane);
    #pragma unroll
    for (int c = 0; c < 4; ++c)
      *(s8v*)(wem + (size_t)tile*2048 + c*512 + lane*8) = pack_pair(acc[2*c], acc[2*c+1]);
  }
}

// ---------------------------------------------------------------------------
// hpass (grid 85 x 3, 512 threads = 8 waves, r24 proven: 108us, VGPR 104).
// {GKe,GKa,GMe,GMa} persistent (128KB, 1 block/CU).
// ---------------------------------------------------------------------------
__global__ __launch_bounds__(512, 1) void hpass(
    const float* __restrict__ nlen, const float* __restrict__ nang,
    const short* __restrict__ wsm, const float* __restrict__ wsb,
    char* __restrict__ ws)
{
  __shared__ short lds[4*16384];
  const int lane = threadIdx.x & 63;
  const int wid  = threadIdx.x >> 6;     // 0..7
  const int t    = blockIdx.y;
  stage_mat512(wsm + (size_t)(8 + t)*16384,  lds,         wid, lane);  // GKe[t]
  stage_mat512(wsm + 3*16384,                lds + 16384, wid, lane);  // GKa
  stage_mat512(wsm + (size_t)(11 + t)*16384, lds + 32768, wid, lane);  // GMe[t]
  stage_mat512(wsm + 4*16384,                lds + 49152, wid, lane);  // GMa
  __syncthreads();
  const int g = lane >> 4, er = lane & 15;
  const float* biasK = wsb + t*128;
  const float* biasM = wsb + 384 + t*128;
  const short* wek = (const short*)(ws + OFF_EK);
  const short* wem = (const short*)(ws + OFF_EM);
  short* wsk  = (short*)(ws + OFF_SK + (size_t)t*12800000ull);
  short* wsm2 = (short*)(ws + OFF_SM + (size_t)t*12800000ull);

  #pragma unroll 1
  for (int tile = blockIdx.x*8 + wid; tile < NTILES; tile += 680){
    const size_t e = (size_t)tile*16 + er;
    const float* lrow = nlen + (e*3 + t)*128;
    const float* arow = nang + (e*3 + t)*128;
    s8v BL[4], BA[4];
    #pragma unroll
    for (int kk = 0; kk < 4; ++kk){
      BL[kk] = load_bfrag(lrow + kk*32 + g*8);
      BA[kk] = load_bfrag(arow + kk*32 + g*8);
    }
    // ---- K path ----
    f4 acc[8];
    #pragma unroll
    for (int c = 0; c < 4; ++c){
      s8v ek8 = *(const s8v*)(wek + (size_t)tile*2048 + c*512 + lane*8);
      f4 b0 = *(const f4*)(biasK + (2*c)*16 + g*4);
      f4 b1 = *(const f4*)(biasK + (2*c+1)*16 + g*4);
      #pragma unroll
      for (int r = 0; r < 4; ++r){ b0[r] += bf2f(ek8[r]); b1[r] += bf2f(ek8[4+r]); }
      acc[2*c] = b0; acc[2*c+1] = b1;
    }
    mm8f(acc, BL, (const s8v*)lds, lane);
    mm8f(acc, BA, (const s8v*)(lds + 16384), lane);
    #pragma unroll
    for (int kk = 0; kk < 4; ++kk){
      s8v S;
      #pragma unroll
      for (int p = 0; p < 4; ++p){
        float x0 = acc[2*kk][p];   S[p]   = f2bf(x0 * sigm(x0));
        float x1 = acc[2*kk+1][p]; S[4+p] = f2bf(x1 * sigm(x1));
      }
      *(s8v*)(wsk + (size_t)tile*2048 + kk*512 + lane*8) = S;
    }
    // ---- M path (same BL/BA) ----
    #pragma unroll
    for (int c = 0; c < 4; ++c){
      s8v em8 = *(const s8v*)(wem + (size_t)tile*2048 + c*512 + lane*8);
      f4 b0 = *(const f4*)(biasM + (2*c)*16 + g*4);
      f4 b1 = *(const f4*)(biasM + (2*c+1)*16 + g*4);
      #pragma unroll
      for (int r = 0; r < 4; ++r){ b0[r] += bf2f(em8[r]); b1[r] += bf2f(em8[4+r]); }
      acc[2*c] = b0; acc[2*c+1] = b1;
    }
    mm8f(acc, BL, (const s8v*)(lds + 32768), lane);
    mm8f(acc, BA, (const s8v*)(lds + 49152), lane);
    #pragma unroll
    for (int kk = 0; kk < 4; ++kk){
      s8v S;
      #pragma unroll
      for (int p = 0; p < 4; ++p){
        float x0 = acc[2*kk][p];   S[p]   = f2bf(x0 * sigm(x0));
        float x1 = acc[2*kk+1][p]; S[4+p] = f2bf(x1 * sigm(x1));
      }
      *(s8v*)(wsm2 + (size_t)tile*2048 + kk*512 + lane*8) = S;
    }
  }
}

// ---------------------------------------------------------------------------
// gfin (512 threads = 8 waves, launch_bounds(512,1)): gpass+fin fused.
// {Wk2,Wm2,Wc} persistent (96KB -> 1 block/CU, 8 waves: latency-tolerant
// on SK/SM reads whether L3-hot or not). Body ~204 regs < 256 cap.
// ---------------------------------------------------------------------------
__global__ __launch_bounds__(512, 1) void gfin(
    const float* __restrict__ edge,
    const float* __restrict__ bk2,  const float* __restrict__ bm2,
    const float* __restrict__ bc,
    const float* __restrict__ g_att, const float* __restrict__ b_att,
    const float* __restrict__ g_bn,  const float* __restrict__ b_bn,
    const short* __restrict__ wsm, const char* __restrict__ ws,
    float* __restrict__ out)
{
  __shared__ short lds[3*16384];
  const int lane = threadIdx.x & 63;
  const int wid  = threadIdx.x >> 6;     // 0..7
  stage_mat512(wsm + 5*16384, lds,         wid, lane);   // Wk2 (dlay)
  stage_mat512(wsm + 6*16384, lds + 16384, wid, lane);   // Wm2 (dlay)
  stage_mat512(wsm + 7*16384, lds + 32768, wid, lane);   // Wc  (dlay)
  __syncthreads();
  const int g = lane >> 4, er = lane & 15;
  const short* wq = (const short*)(ws + OFF_Q);

  #pragma unroll 1
  for (int tile = blockIdx.x*8 + wid; tile < NTILES; tile += 2048){
    const size_t e = (size_t)tile*16 + er;
    f4 gm[8], acc[8], gate[8];
    #pragma unroll
    for (int mb = 0; mb < 8; ++mb){ f4 z = {0.f,0.f,0.f,0.f}; gm[mb] = z; }

    #pragma unroll 1
    for (int t = 0; t < 3; ++t){
      const short* wsk  = (const short*)(ws + OFF_SK + (size_t)t*12800000ull);
      const short* wsm2 = (const short*)(ws + OFF_SM + (size_t)t*12800000ull);
      s8v SF[4];
      #pragma unroll
      for (int kk = 0; kk < 4; ++kk)
        SF[kk] = *(const s8v*)(wsk + (size_t)tile*2048 + kk*512 + lane*8);
      #pragma unroll
      for (int mb = 0; mb < 8; ++mb) acc[mb] = *(const f4*)(bk2 + mb*16 + g*4);
      mm8f(acc, SF, (const s8v*)lds, lane);

      float sm = 0.f, ssq = 0.f;
      #pragma unroll
      for (int c = 0; c < 4; ++c){
        s8v q8 = *(const s8v*)(wq + (size_t)tile*2048 + c*512 + lane*8);
        #pragma unroll
        for (int r = 0; r < 4; ++r){
          float a = bf2f(q8[r])   * acc[2*c][r]   * 0.08838834764831845f;
          float b = bf2f(q8[4+r]) * acc[2*c+1][r] * 0.08838834764831845f;
          acc[2*c][r] = a; acc[2*c+1][r] = b;
          sm += a + b; ssq += a*a + b*b;
        }
      }
      sm  += __shfl_xor(sm, 16);  sm  += __shfl_xor(sm, 32);
      ssq += __shfl_xor(ssq, 16); ssq += __shfl_xor(ssq, 32);
      float mean = sm * (1.f/128.f);
      float rstd = rsqrtf(ssq * (1.f/128.f) - mean*mean + 1e-5f);
      #pragma unroll
      for (int mb = 0; mb < 8; ++mb){
        f4 ga = *(const f4*)(g_att + mb*16 + g*4);
        f4 bb = *(const f4*)(b_att + mb*16 + g*4);
        #pragma unroll
        for (int r = 0; r < 4; ++r)
          gate[mb][r] = sigm((acc[mb][r] - mean)*rstd*ga[r] + bb[r]);
      }

      #pragma unroll
      for (int kk = 0; kk < 4; ++kk)
        SF[kk] = *(const s8v*)(wsm2 + (size_t)tile*2048 + kk*512 + lane*8);
      #pragma unroll
      for (int mb = 0; mb < 8; ++mb) acc[mb] = *(const f4*)(bm2 + mb*16 + g*4);
      mm8f(acc, SF, (const s8v*)(lds + 16384), lane);
      #pragma unroll
      for (int mb = 0; mb < 8; ++mb){
        #pragma unroll
        for (int r = 0; r < 4; ++r) gm[mb][r] += acc[mb][r] * gate[mb][r];
      }
    }

    // out = softplus(edge + LN(gm@Wc + 3bc))
    s8v GF[4];
    #pragma unroll
    for (int c = 0; c < 4; ++c) GF[c] = pack_pair(gm[2*c], gm[2*c+1]);
    #pragma unroll
    for (int mb = 0; mb < 8; ++mb){
      f4 b = *(const f4*)(bc + mb*16 + g*4);
      #pragma unroll
      for (int r = 0; r < 4; ++r) b[r] *= 3.f;
      acc[mb] = b;
    }
    mm8f(acc, GF, (const s8v*)(lds + 32768), lane);

    float sm = 0.f, ssq = 0.f;
    #pragma unroll
    for (int mb = 0; mb < 8; ++mb){
      #pragma unroll
      for (int r = 0; r < 4; ++r){ sm += acc[mb][r]; ssq += acc[mb][r]*acc[mb][r]; }
    }
    sm  += __shfl_xor(sm, 16);  sm  += __shfl_xor(sm, 32);
    ssq += __shfl_xor(ssq, 16); ssq += __shfl_xor(ssq, 32);
    float mean = sm * (1.f/128.f);
    float rstd = rsqrtf(ssq * (1.f/128.f) - mean*mean + 1e-5f);

    const float* erow = edge + e*128;
    #pragma unroll
    for (int mb = 0; mb < 8; ++mb){
      f4 ev  = *(const f4*)(erow + mb*16 + g*4);
      f4 gv  = *(const f4*)(g_bn + mb*16 + g*4);
      f4 bv2 = *(const f4*)(b_bn + mb*16 + g*4);
      f4 o;
      #pragma unroll
      for (int r = 0; r < 4; ++r){
        float x = ev[r] + (acc[mb][r] - mean)*rstd*gv[r] + bv2[r];
        o[r] = (x > 20.f) ? x : __logf(1.f + __expf(x));
      }
      *(f4*)(out + e*128 + mb*16 + g*4) = o;
    }
  }
}

// ---------------------------------------------------------------------------
// Fallback: r2 fused kernel (known-good), unchanged.
// ---------------------------------------------------------------------------
__global__ __launch_bounds__(256) void edge_fused(
    const float* __restrict__ edge, const float* __restrict__ nlen, const float* __restrict__ nang,
    const float* __restrict__ bq,   const float* __restrict__ bk2,  const float* __restrict__ bm2,
    const float* __restrict__ bc,
    const float* __restrict__ g_att, const float* __restrict__ b_att,
    const float* __restrict__ g_bn,  const float* __restrict__ b_bn,
    const short* __restrict__ wsm,  const float* __restrict__ wsb,
    float* __restrict__ out)
{
  __shared__ short smem[2*16384];
  const int lane = threadIdx.x & 63;
  const int wid  = threadIdx.x >> 6;
  int tile = blockIdx.x*4 + wid;
  if (tile > NTILES-1) tile = NTILES-1;
  const int g  = lane >> 4;
  const int er = lane & 15;
  const size_t e = (size_t)tile*16 + er;
  const float* erow = edge + e*128;

  stage_mat(wsm + 0*16384, smem, wid, lane);
  s8v BE[4];
  #pragma unroll
  for (int kk = 0; kk < 4; ++kk) BE[kk] = load_bfrag(erow + kk*32 + g*8);
  f4 acc[8], gm[8];
  s4v qb[8], ekb[8], emb[8], gateb[8];
  s8v S[4], BL[4], BA[4];
  #pragma unroll
  for (int mb = 0; mb < 8; ++mb){ f4 z = {0.f,0.f,0.f,0.f}; gm[mb] = z; }
  __syncthreads();

  stage_mat(wsm + 1*16384, smem + 16384, wid, lane);
  #pragma unroll
  for (int mb = 0; mb < 8; ++mb) acc[mb] = *(const f4*)(bq + mb*16 + g*4);
  mm8l(acc, BE, (const s8v*)smem, lane);
  #pragma unroll
  for (int mb = 0; mb < 8; ++mb){
    s4v t4; t4[0]=f2bf(acc[mb][0]); t4[1]=f2bf(acc[mb][1]); t4[2]=f2bf(acc[mb][2]); t4[3]=f2bf(acc[mb][3]);
    qb[mb] = t4;
  }
  __syncthreads();

  stage_mat(wsm + 2*16384, smem, wid, lane);
  #pragma unroll
  for (int mb = 0; mb < 8; ++mb){ f4 z = {0.f,0.f,0.f,0.f}; acc[mb] = z; }
  mm8l(acc, BE, (const s8v*)(smem + 16384), lane);
  #pragma unroll
  for (int mb = 0; mb < 8; ++mb){
    s4v t4; t4[0]=f2bf(acc[mb][0]); t4[1]=f2bf(acc[mb][1]); t4[2]=f2bf(acc[mb][2]); t4[3]=f2bf(acc[mb][3]);
    ekb[mb] = t4;
  }
  __syncthreads();

  stage_mat(wsm + 8*16384, smem + 16384, wid, lane);
  #pragma unroll
  for (int mb = 0; mb < 8; ++mb){ f4 z = {0.f,0.f,0.f,0.f}; acc[mb] = z; }
  mm8l(acc, BE, (const s8v*)smem, lane);
  #pragma unroll
  for (int mb = 0; mb < 8; ++mb){
    s4v t4; t4[0]=f2bf(acc[mb][0]); t4[1]=f2bf(acc[mb][1]); t4[2]=f2bf(acc[mb][2]); t4[3]=f2bf(acc[mb][3]);
    emb[mb] = t4;
  }
  {
    const float* lrow = nlen + e*3*128;
    const float* arow = nang + e*3*128;
    #pragma unroll
    for (int kk = 0; kk < 4; ++kk){
      BL[kk] = load_bfrag(lrow + kk*32 + g*8);
      BA[kk] = load_bfrag(arow + kk*32 + g*8);
    }
  }
  __syncthreads();

  int cur = 1;
  #pragma unroll 1
  for (int t = 0; t < 3; ++t){
    stage_mat(wsm + 3*16384, smem + (cur^1)*16384, wid, lane);
    #pragma unroll
    for (int mb = 0; mb < 8; ++mb){
      f4 b = *(const f4*)(wsb + t*128 + mb*16 + g*4);
      #pragma unroll
      for (int r = 0; r < 4; ++r) b[r] += bf2f(ekb[mb][r]);
      acc[mb] = b;
    }
    mm8l(acc, BL, (const s8v*)(smem + cur*16384), lane);
    __syncthreads(); cur ^= 1;

    stage_mat(wsm + 5*16384, smem + (cur^1)*16384, wid, lane);
    mm8l(acc, BA, (const s8v*)(smem + cur*16384), lane);
    #pragma unroll
    for (int kk = 0; kk < 4; ++kk){
      #pragma unroll
      for (int p = 0; p < 4; ++p){
        float x0 = acc[2*kk][p];   S[kk][p]   = f2bf(x0 * sigm(x0));
        float x1 = acc[2*kk+1][p]; S[kk][4+p] = f2bf(x1 * sigm(x1));
      }
    }
    __syncthreads(); cur ^= 1;

    stage_mat(wsm + (size_t)(11+t)*16384, smem + (cur^1)*16384, wid, lane);
    #pragma unroll
    for (int mb = 0; mb < 8; ++mb) acc[mb] = *(const f4*)(bk2 + mb*16 + g*4);
    mm8l(acc, S, (const s8v*)(smem + cur*16384), lane);
    {
      float sm = 0.f, ssq = 0.f;
      #pragma unroll
      for (int mb = 0; mb < 8; ++mb){
        #pragma unroll
        for (int r = 0; r < 4; ++r){
          float a = bf2f(qb[mb][r]) * acc[mb][r] * 0.08838834764831845f;
          acc[mb][r] = a; sm += a; ssq += a*a;
        }
      }
      sm  += __shfl_xor(sm, 16);  sm  += __shfl_xor(sm, 32);
      ssq += __shfl_xor(ssq, 16); ssq += __shfl_xor(ssq, 32);
      float mean = sm * (1.f/128.f);
      float rstd = rsqrtf(ssq * (1.f/128.f) - mean*mean + 1e-5f);
      #pragma unroll
      for (int mb = 0; mb < 8; ++mb){
        f4 ga = *(const f4*)(g_att + mb*16 + g*4);
        f4 bb = *(const f4*)(b_att + mb*16 + g*4);
        s4v t4;
        #pragma unroll
        for (int r = 0; r < 4; ++r)
          t4[r] = f2bf(sigm((acc[mb][r] - mean)*rstd*ga[r] + bb[r]));
        gateb[mb] = t4;
      }
    }
    __syncthreads(); cur ^= 1;

    stage_mat(wsm + 4*16384, smem + (cur^1)*16384, wid, lane);
    #pragma unroll
    for (int mb = 0; mb < 8; ++mb){
      f4 b = *(const f4*)(wsb + 384 + t*128 + mb*16 + g*4);
      #pragma unroll
      for (int r = 0; r < 4; ++r) b[r] += bf2f(emb[mb][r]);
      acc[mb] = b;
    }
    mm8l(acc, BL, (const s8v*)(smem + cur*16384), lane);
    __syncthreads(); cur ^= 1;

    stage_mat(wsm + 6*16384, smem + (cur^1)*16384, wid, lane);
    mm8l(acc, BA, (const s8v*)(smem + cur*16384), lane);
    #pragma unroll
    for (int kk = 0; kk < 4; ++kk){
      #pragma unroll
      for (int p = 0; p < 4; ++p){
        float x0 = acc[2*kk][p];   S[kk][p]   = f2bf(x0 * sigm(x0));
        float x1 = acc[2*kk+1][p]; S[kk][4+p] = f2bf(x1 * sigm(x1));
      }
    }
    __syncthreads(); cur ^= 1;

    stage_mat(wsm + (size_t)(t < 2 ? 9 + t : 7)*16384, smem + (cur^1)*16384, wid, lane);
    #pragma unroll
    for (int mb = 0; mb < 8; ++mb) acc[mb] = *(const f4*)(bm2 + mb*16 + g*4);
    mm8l(acc, S, (const s8v*)(smem + cur*16384), lane);
    if (t < 2){
      const float* lrow = nlen + (e*3 + t + 1)*128;
      const float* arow = nang + (e*3 + t + 1)*128;
      #pragma unroll
      for (int kk = 0; kk < 4; ++kk){
        BL[kk] = load_bfrag(lrow + kk*32 + g*8);
        BA[kk] = load_bfrag(arow + kk*32 + g*8);
      }
    }
    #pragma unroll
    for (int mb = 0; mb < 8; ++mb){
      #pragma unroll
      for (int r = 0; r < 4; ++r) gm[mb][r] += acc[mb][r] * bf2f(gateb[mb][r]);
    }
    __syncthreads(); cur ^= 1;
  }

  s8v GF[4];
  #pragma unroll
  for (int kk = 0; kk < 4; ++kk){
    #pragma unroll
    for (int p = 0; p < 4; ++p){
      GF[kk][p]   = f2bf(gm[2*kk][p]);
      GF[kk][4+p] = f2bf(gm[2*kk+1][p]);
    }
  }
  #pragma unroll
  for (int mb = 0; mb < 8; ++mb){
    f4 b = *(const f4*)(bc + mb*16 + g*4);
    #pragma unroll
    for (int r = 0; r < 4; ++r) b[r] *= 3.f;
    acc[mb] = b;
  }
  mm8l(acc, GF, (const s8v*)(smem + cur*16384), lane);

  float sm = 0.f, ssq = 0.f;
  #pragma unroll
  for (int mb = 0; mb < 8; ++mb){
    #pragma unroll
    for (int r = 0; r < 4; ++r){ sm += acc[mb][r]; ssq += acc[mb][r]*acc[mb][r]; }
  }
  sm  += __shfl_xor(sm, 16);  sm  += __shfl_xor(sm, 32);
  ssq += __shfl_xor(ssq, 16); ssq += __shfl_xor(ssq, 32);
  float mean = sm * (1.f/128.f);
  float rstd = rsqrtf(ssq * (1.f/128.f) - mean*mean + 1e-5f);

  #pragma unroll
  for (int mb = 0; mb < 8; ++mb){
    f4 ev  = *(const f4*)(erow + mb*16 + g*4);
    f4 gv  = *(const f4*)(g_bn + mb*16 + g*4);
    f4 bv2 = *(const f4*)(b_bn + mb*16 + g*4);
    f4 o;
    #pragma unroll
    for (int r = 0; r < 4; ++r){
      float x = ev[r] + (acc[mb][r] - mean)*rstd*gv[r] + bv2[r];
      o[r] = (x > 20.f) ? x : log1pf(__expf(x));
    }
    *(f4*)(out + e*128 + mb*16 + g*4) = o;
  }
}

extern "C" void kernel_launch(void* const* d_in, const int* in_sizes, int n_in,
                              void* d_out, int out_size, void* d_ws, size_t ws_size,
                              hipStream_t stream)
{
  const float* edge = (const float*)d_in[0];
  const float* nlen = (const float*)d_in[1];
  const float* nang = (const float*)d_in[2];
  const float* Wq  = (const float*)d_in[3];
  const float* bq  = (const float*)d_in[4];
  const float* Wk  = (const float*)d_in[5];
  const float* bk  = (const float*)d_in[6];
  const float* Wv  = (const float*)d_in[7];
  const float* bv  = (const float*)d_in[8];
  const float* Wke = (const float*)d_in[9];
  const float* bke = (const float*)d_in[10];
  const float* Wve = (const float*)d_in[11];
  const float* bve = (const float*)d_in[12];
  const float* We  = (const float*)d_in[13];
  const float* Wc  = (const float*)d_in[14];
  const float* bc  = (const float*)d_in[15];
  const float* Wk1 = (const float*)d_in[16];
  const float* bk1 = (const float*)d_in[17];
  const float* Wk2 = (const float*)d_in[18];
  const float* bk2 = (const float*)d_in[19];
  const float* Wm1 = (const float*)d_in[20];
  const float* bm1 = (const float*)d_in[21];
  const float* Wm2 = (const float*)d_in[22];
  const float* bm2 = (const float*)d_in[23];
  const float* g_att = (const float*)d_in[24];
  const float* b_att = (const float*)d_in[25];
  const float* g_bn  = (const float*)d_in[26];
  const float* b_bn  = (const float*)d_in[27];

  short* wsm = (short*)d_ws;
  float* wsb = (float*)((char*)d_ws + OFF_WSB);
  char*  ws  = (char*)d_ws;

  pack_weights<<<dim3(14*64), dim3(256), 0, stream>>>(
      Wq, Wk, Wv, Wke, Wve, We, Wc, Wk1, Wk2, Wm1, Wm2, wsm);
  make_biases<<<dim3(6), dim3(128), 0, stream>>>(
      bk, bke, bk1, bv, bve, bm1, Wk1, Wm1, wsb);

  if (ws_size >= WS_NEED){
    proj<<<dim3(256), dim3(512), 0, stream>>>(edge, bq, wsm, ws);
    hpass<<<dim3(85, 3), dim3(512), 0, stream>>>(nlen, nang, wsm, wsb, ws);
    gfin<<<dim3(256), dim3(512), 0, stream>>>(
        edge, bk2, bm2, bc, g_att, b_att, g_bn, b_bn, wsm, ws, (float*)d_out);
  } else {
    edge_fused<<<dim3((NTILES + 3)/4), dim3(256), 0, stream>>>(
        edge, nlen, nang, bq, bk2, bm2, bc, g_att, b_att, g_bn, b_bn,
        wsm, wsb, (float*)d_out);
  }
}

// Round 26
// 171.623 us; speedup vs baseline: 1.3728x; 1.3728x over previous
//
#include <hip/hip_runtime.h>

#define E_TOTAL 50000
#define NTILES  3125      // E_TOTAL / 16, exact

// ---- workspace map (bytes) ----
#define OFF_WSB 458752ull
#define OFF_Q   524288ull
#define OFF_EK  (OFF_Q  + 12800000ull)
#define OFF_EM  (OFF_EK + 12800000ull)
#define OFF_SK  (OFF_EM + 12800000ull)   // 3 bufs, stride 12.8MB
#define OFF_SM  (OFF_SK + 38400000ull)   // 3 bufs, stride 12.8MB
#define WS_NEED (OFF_SM + 38400000ull)   // 115,724,288 B

typedef float f4  __attribute__((ext_vector_type(4)));
typedef short s8v __attribute__((ext_vector_type(8)));
typedef short s4v __attribute__((ext_vector_type(4)));

typedef __attribute__((address_space(3))) unsigned lds_u32;
typedef __attribute__((address_space(1))) const unsigned g_u32;

__device__ __forceinline__ short f2bf(float x){
  unsigned u = __builtin_bit_cast(unsigned, x);
  u += 0x7fffu + ((u >> 16) & 1u);
  return (short)(u >> 16);
}
__device__ __forceinline__ float bf2f(short s){
  unsigned u = ((unsigned)(unsigned short)s) << 16;
  return __builtin_bit_cast(float, u);
}
__device__ __forceinline__ float sigm(float x){ return 1.f/(1.f + __expf(-x)); }

__device__ __forceinline__ s8v load_bfrag(const float* p){
  f4 a = *(const f4*)p;
  f4 b = *(const f4*)(p + 4);
  s8v r;
  r[0]=f2bf(a[0]); r[1]=f2bf(a[1]); r[2]=f2bf(a[2]); r[3]=f2bf(a[3]);
  r[4]=f2bf(b[0]); r[5]=f2bf(b[1]); r[6]=f2bf(b[2]); r[7]=f2bf(b[3]);
  return r;
}

// Unfenced GEMM (fused fallback only).
__device__ __forceinline__ void mm8l(f4* acc, const s8v* B, const s8v* A, int lane){
  #pragma unroll
  for (int mb = 0; mb < 8; ++mb){
    #pragma unroll
    for (int kk = 0; kk < 4; ++kk){
      s8v af = A[(mb*4 + kk)*64 + lane];
      acc[mb] = __builtin_amdgcn_mfma_f32_16x16x32_bf16(af, B[kk], acc[mb], 0, 0, 0);
    }
  }
}

// FENCED GEMM: sched_barrier every 2 mb-blocks caps in-flight LDS A-reads
// (prevents whole-matrix hoist -> spills; proven clean r14-r24).
__device__ __forceinline__ void mm8f(f4* acc, const s8v* B, const s8v* A, int lane){
  #pragma unroll
  for (int mb = 0; mb < 8; mb += 2){
    #pragma unroll
    for (int m2 = 0; m2 < 2; ++m2){
      #pragma unroll
      for (int kk = 0; kk < 4; ++kk){
        s8v af = A[((mb+m2)*4 + kk)*64 + lane];
        acc[mb+m2] = __builtin_amdgcn_mfma_f32_16x16x32_bf16(af, B[kk], acc[mb+m2], 0, 0, 0);
      }
    }
    __builtin_amdgcn_sched_barrier(0);
  }
}

// 32KB matrix stage, 256-thread block (8 x 16B per thread)
__device__ __forceinline__ void stage_mat(const short* __restrict__ src,
                                          short* dst, int wid, int lane){
  #pragma unroll
  for (int j = 0; j < 8; ++j){
    const short* gsrc = src + j*2048 + wid*512 + lane*8;
    short* ldst = dst + j*2048 + wid*512;
    __builtin_amdgcn_global_load_lds((g_u32*)(const void*)gsrc, (lds_u32*)(void*)ldst, 16, 0, 0);
  }
}
// 32KB matrix stage, 512-thread block (4 x 16B per thread)
__device__ __forceinline__ void stage_mat512(const short* __restrict__ src,
                                             short* dst, int wid, int lane){
  #pragma unroll
  for (int j = 0; j < 4; ++j){
    const short* gsrc = src + j*4096 + wid*512 + lane*8;
    short* ldst = dst + j*4096 + wid*512;
    __builtin_amdgcn_global_load_lds((g_u32*)(const void*)gsrc, (lds_u32*)(void*)ldst, 16, 0, 0);
  }
}

__device__ __forceinline__ s8v pack_pair(const f4& a0, const f4& a1){
  s8v o;
  #pragma unroll
  for (int p = 0; p < 4; ++p){ o[p] = f2bf(a0[p]); o[4+p] = f2bf(a1[p]); }
  return o;
}

// ---------------------------------------------------------------------------
// pack_weights / make_biases (unchanged)
// ---------------------------------------------------------------------------
__global__ __launch_bounds__(256) void pack_weights(
    const float* __restrict__ Wq, const float* __restrict__ Wk, const float* __restrict__ Wv,
    const float* __restrict__ Wke, const float* __restrict__ Wve, const float* __restrict__ We,
    const float* __restrict__ Wc, const float* __restrict__ Wk1, const float* __restrict__ Wk2,
    const float* __restrict__ Wm1, const float* __restrict__ Wm2,
    short* __restrict__ wsm)
{
  int mi   = blockIdx.x >> 6;
  int elem = ((blockIdx.x & 63) << 8) + threadIdx.x;
  int p  = elem & 7;
  int l  = (elem >> 3) & 63;
  int kk = (elem >> 9) & 3;
  int mb = elem >> 11;
  int gg = l >> 4;
  int m  = mb*16 + (l & 15);
  bool dlay = (mi == 5) || (mi == 6) || (mi == 7);
  int k = dlay ? (kk*32 + ((p < 4) ? (gg*4 + p) : (16 + gg*4 + (p - 4))))
               : (kk*32 + gg*8 + p);

  const float* X = nullptr; const float* Y = nullptr; const float* W = nullptr;
  switch (mi){
    case 0: W = Wq; break;
    case 1: X = Wk; Y = Wk1;            break;
    case 2: X = Wv; Y = Wm1;            break;
    case 3: X = We; Y = Wk1 + 256*128;  break;
    case 4: X = We; Y = Wm1 + 256*128;  break;
    case 5: W = Wk2; break;
    case 6: W = Wm2; break;
    case 7: W = Wc;  break;
    default:
      if (mi < 11){ X = Wke + (mi-8)*16384;  Y = Wk1 + 128*128; }
      else        { X = Wve + (mi-11)*16384; Y = Wm1 + 128*128; }
  }
  float v;
  if (W){
    v = W[k*128 + m];
  } else {
    v = 0.f;
    for (int j = 0; j < 128; ++j) v += X[k*128 + j] * Y[j*128 + m];
  }
  wsm[(size_t)mi*16384 + elem] = f2bf(v);
}

__global__ __launch_bounds__(128) void make_biases(
    const float* __restrict__ bk,  const float* __restrict__ bke, const float* __restrict__ bk1,
    const float* __restrict__ bv,  const float* __restrict__ bve, const float* __restrict__ bm1,
    const float* __restrict__ Wk1, const float* __restrict__ Wm1,
    float* __restrict__ wsb)
{
  int b = blockIdx.x;
  int t = b % 3;
  bool isM = b >= 3;
  int o = threadIdx.x;
  const float* W  = isM ? Wm1 : Wk1;
  const float* b0 = isM ? bv  : bk;
  const float* be = (isM ? bve : bke) + t*128;
  const float* b1 = isM ? bm1 : bk1;
  float v = b1[o];
  for (int j = 0; j < 128; ++j)
    v += b0[j]*W[j*128 + o] + be[j]*W[(128 + j)*128 + o];
  wsb[b*128 + o] = v;
}

// ---------------------------------------------------------------------------
// proj (256 threads): q^/ek/em bf16 pair-layout. {Wq,GK,GM} persistent (96KB).
// 256 threads: body ~150 regs > 128-VGPR clamp that 512-thread blocks get
// (r25 falsified 512-thr here), so stay at 4 waves.
// ---------------------------------------------------------------------------
__global__ __launch_bounds__(256) void proj(
    const float* __restrict__ edge, const float* __restrict__ bq,
    const short* __restrict__ wsm, char* __restrict__ ws)
{
  __shared__ short lds[3*16384];
  const int lane = threadIdx.x & 63;
  const int wid  = threadIdx.x >> 6;
  stage_mat(wsm + 0*16384, lds,          wid, lane);
  stage_mat(wsm + 1*16384, lds + 16384,  wid, lane);
  stage_mat(wsm + 2*16384, lds + 32768,  wid, lane);
  __syncthreads();
  const int g = lane >> 4, er = lane & 15;
  short* wq  = (short*)(ws + OFF_Q);
  short* wek = (short*)(ws + OFF_EK);
  short* wem = (short*)(ws + OFF_EM);

  #pragma unroll 1
  for (int tile = blockIdx.x*4 + wid; tile < NTILES; tile += 1024){
    const float* erow = edge + ((size_t)tile*16 + er)*128;
    s8v BE[4];
    #pragma unroll
    for (int kk = 0; kk < 4; ++kk) BE[kk] = load_bfrag(erow + kk*32 + g*8);

    f4 acc[8];
    #pragma unroll
    for (int mb = 0; mb < 8; ++mb) acc[mb] = *(const f4*)(bq + mb*16 + g*4);
    mm8f(acc, BE, (const s8v*)lds, lane);
    #pragma unroll
    for (int c = 0; c < 4; ++c)
      *(s8v*)(wq + (size_t)tile*2048 + c*512 + lane*8) = pack_pair(acc[2*c], acc[2*c+1]);

    #pragma unroll
    for (int mb = 0; mb < 8; ++mb){ f4 z = {0.f,0.f,0.f,0.f}; acc[mb] = z; }
    mm8f(acc, BE, (const s8v*)(lds + 16384), lane);
    #pragma unroll
    for (int c = 0; c < 4; ++c)
      *(s8v*)(wek + (size_t)tile*2048 + c*512 + lane*8) = pack_pair(acc[2*c], acc[2*c+1]);

    #pragma unroll
    for (int mb = 0; mb < 8; ++mb){ f4 z = {0.f,0.f,0.f,0.f}; acc[mb] = z; }
    mm8f(acc, BE, (const s8v*)(lds + 32768), lane);
    #pragma unroll
    for (int c = 0; c < 4; ++c)
      *(s8v*)(wem + (size_t)tile*2048 + c*512 + lane*8) = pack_pair(acc[2*c], acc[2*c+1]);
  }
}

// ---------------------------------------------------------------------------
// hpass (grid 85 x 3, 512 threads = 8 waves; r24 proven: 108us, VGPR 104 —
// body fits under the 128-VGPR 512-thread clamp, so no spill).
// {GKe,GKa,GMe,GMa} persistent (128KB, 1 block/CU).
// ---------------------------------------------------------------------------
__global__ __launch_bounds__(512, 1) void hpass(
    const float* __restrict__ nlen, const float* __restrict__ nang,
    const short* __restrict__ wsm, const float* __restrict__ wsb,
    char* __restrict__ ws)
{
  __shared__ short lds[4*16384];
  const int lane = threadIdx.x & 63;
  const int wid  = threadIdx.x >> 6;     // 0..7
  const int t    = blockIdx.y;
  stage_mat512(wsm + (size_t)(8 + t)*16384,  lds,         wid, lane);  // GKe[t]
  stage_mat512(wsm + 3*16384,                lds + 16384, wid, lane);  // GKa
  stage_mat512(wsm + (size_t)(11 + t)*16384, lds + 32768, wid, lane);  // GMe[t]
  stage_mat512(wsm + 4*16384,                lds + 49152, wid, lane);  // GMa
  __syncthreads();
  const int g = lane >> 4, er = lane & 15;
  const float* biasK = wsb + t*128;
  const float* biasM = wsb + 384 + t*128;
  const short* wek = (const short*)(ws + OFF_EK);
  const short* wem = (const short*)(ws + OFF_EM);
  short* wsk  = (short*)(ws + OFF_SK + (size_t)t*12800000ull);
  short* wsm2 = (short*)(ws + OFF_SM + (size_t)t*12800000ull);

  #pragma unroll 1
  for (int tile = blockIdx.x*8 + wid; tile < NTILES; tile += 680){
    const size_t e = (size_t)tile*16 + er;
    const float* lrow = nlen + (e*3 + t)*128;
    const float* arow = nang + (e*3 + t)*128;
    s8v BL[4], BA[4];
    #pragma unroll
    for (int kk = 0; kk < 4; ++kk){
      BL[kk] = load_bfrag(lrow + kk*32 + g*8);
      BA[kk] = load_bfrag(arow + kk*32 + g*8);
    }
    // ---- K path ----
    f4 acc[8];
    #pragma unroll
    for (int c = 0; c < 4; ++c){
      s8v ek8 = *(const s8v*)(wek + (size_t)tile*2048 + c*512 + lane*8);
      f4 b0 = *(const f4*)(biasK + (2*c)*16 + g*4);
      f4 b1 = *(const f4*)(biasK + (2*c+1)*16 + g*4);
      #pragma unroll
      for (int r = 0; r < 4; ++r){ b0[r] += bf2f(ek8[r]); b1[r] += bf2f(ek8[4+r]); }
      acc[2*c] = b0; acc[2*c+1] = b1;
    }
    mm8f(acc, BL, (const s8v*)lds, lane);
    mm8f(acc, BA, (const s8v*)(lds + 16384), lane);
    #pragma unroll
    for (int kk = 0; kk < 4; ++kk){
      s8v S;
      #pragma unroll
      for (int p = 0; p < 4; ++p){
        float x0 = acc[2*kk][p];   S[p]   = f2bf(x0 * sigm(x0));
        float x1 = acc[2*kk+1][p]; S[4+p] = f2bf(x1 * sigm(x1));
      }
      *(s8v*)(wsk + (size_t)tile*2048 + kk*512 + lane*8) = S;
    }
    // ---- M path (same BL/BA) ----
    #pragma unroll
    for (int c = 0; c < 4; ++c){
      s8v em8 = *(const s8v*)(wem + (size_t)tile*2048 + c*512 + lane*8);
      f4 b0 = *(const f4*)(biasM + (2*c)*16 + g*4);
      f4 b1 = *(const f4*)(biasM + (2*c+1)*16 + g*4);
      #pragma unroll
      for (int r = 0; r < 4; ++r){ b0[r] += bf2f(em8[r]); b1[r] += bf2f(em8[4+r]); }
      acc[2*c] = b0; acc[2*c+1] = b1;
    }
    mm8f(acc, BL, (const s8v*)(lds + 32768), lane);
    mm8f(acc, BA, (const s8v*)(lds + 49152), lane);
    #pragma unroll
    for (int kk = 0; kk < 4; ++kk){
      s8v S;
      #pragma unroll
      for (int p = 0; p < 4; ++p){
        float x0 = acc[2*kk][p];   S[p]   = f2bf(x0 * sigm(x0));
        float x1 = acc[2*kk+1][p]; S[4+p] = f2bf(x1 * sigm(x1));
      }
      *(s8v*)(wsm2 + (size_t)tile*2048 + kk*512 + lane*8) = S;
    }
  }
}

// ---------------------------------------------------------------------------
// gfin (256 threads): gpass+fin fused. {Wk2,Wm2,Wc} persistent (96KB).
// Body 204 regs > 128-VGPR 512-thread clamp (r25 falsified 512-thr: 97MB
// spill), so stay at 256 threads / 4 waves. Runs right after hpass so
// SK/SM are L3-hot (~35us then).
// ---------------------------------------------------------------------------
__global__ __launch_bounds__(256) void gfin(
    const float* __restrict__ edge,
    const float* __restrict__ bk2,  const float* __restrict__ bm2,
    const float* __restrict__ bc,
    const float* __restrict__ g_att, const float* __restrict__ b_att,
    const float* __restrict__ g_bn,  const float* __restrict__ b_bn,
    const short* __restrict__ wsm, const char* __restrict__ ws,
    float* __restrict__ out)
{
  __shared__ short lds[3*16384];
  const int lane = threadIdx.x & 63;
  const int wid  = threadIdx.x >> 6;
  stage_mat(wsm + 5*16384, lds,         wid, lane);   // Wk2 (dlay)
  stage_mat(wsm + 6*16384, lds + 16384, wid, lane);   // Wm2 (dlay)
  stage_mat(wsm + 7*16384, lds + 32768, wid, lane);   // Wc  (dlay)
  __syncthreads();
  const int g = lane >> 4, er = lane & 15;
  const short* wq = (const short*)(ws + OFF_Q);

  #pragma unroll 1
  for (int tile = blockIdx.x*4 + wid; tile < NTILES; tile += 1024){
    const size_t e = (size_t)tile*16 + er;
    f4 gm[8], acc[8], gate[8];
    #pragma unroll
    for (int mb = 0; mb < 8; ++mb){ f4 z = {0.f,0.f,0.f,0.f}; gm[mb] = z; }

    #pragma unroll 1
    for (int t = 0; t < 3; ++t){
      const short* wsk  = (const short*)(ws + OFF_SK + (size_t)t*12800000ull);
      const short* wsm2 = (const short*)(ws + OFF_SM + (size_t)t*12800000ull);
      s8v SF[4];
      #pragma unroll
      for (int kk = 0; kk < 4; ++kk)
        SF[kk] = *(const s8v*)(wsk + (size_t)tile*2048 + kk*512 + lane*8);
      #pragma unroll
      for (int mb = 0; mb < 8; ++mb) acc[mb] = *(const f4*)(bk2 + mb*16 + g*4);
      mm8f(acc, SF, (const s8v*)lds, lane);

      float sm = 0.f, ssq = 0.f;
      #pragma unroll
      for (int c = 0; c < 4; ++c){
        s8v q8 = *(const s8v*)(wq + (size_t)tile*2048 + c*512 + lane*8);
        #pragma unroll
        for (int r = 0; r < 4; ++r){
          float a = bf2f(q8[r])   * acc[2*c][r]   * 0.08838834764831845f;
          float b = bf2f(q8[4+r]) * acc[2*c+1][r] * 0.08838834764831845f;
          acc[2*c][r] = a; acc[2*c+1][r] = b;
          sm += a + b; ssq += a*a + b*b;
        }
      }
      sm  += __shfl_xor(sm, 16);  sm  += __shfl_xor(sm, 32);
      ssq += __shfl_xor(ssq, 16); ssq += __shfl_xor(ssq, 32);
      float mean = sm * (1.f/128.f);
      float rstd = rsqrtf(ssq * (1.f/128.f) - mean*mean + 1e-5f);
      #pragma unroll
      for (int mb = 0; mb < 8; ++mb){
        f4 ga = *(const f4*)(g_att + mb*16 + g*4);
        f4 bb = *(const f4*)(b_att + mb*16 + g*4);
        #pragma unroll
        for (int r = 0; r < 4; ++r)
          gate[mb][r] = sigm((acc[mb][r] - mean)*rstd*ga[r] + bb[r]);
      }

      #pragma unroll
      for (int kk = 0; kk < 4; ++kk)
        SF[kk] = *(const s8v*)(wsm2 + (size_t)tile*2048 + kk*512 + lane*8);
      #pragma unroll
      for (int mb = 0; mb < 8; ++mb) acc[mb] = *(const f4*)(bm2 + mb*16 + g*4);
      mm8f(acc, SF, (const s8v*)(lds + 16384), lane);
      #pragma unroll
      for (int mb = 0; mb < 8; ++mb){
        #pragma unroll
        for (int r = 0; r < 4; ++r) gm[mb][r] += acc[mb][r] * gate[mb][r];
      }
    }

    // out = softplus(edge + LN(gm@Wc + 3bc))
    s8v GF[4];
    #pragma unroll
    for (int c = 0; c < 4; ++c) GF[c] = pack_pair(gm[2*c], gm[2*c+1]);
    #pragma unroll
    for (int mb = 0; mb < 8; ++mb){
      f4 b = *(const f4*)(bc + mb*16 + g*4);
      #pragma unroll
      for (int r = 0; r < 4; ++r) b[r] *= 3.f;
      acc[mb] = b;
    }
    mm8f(acc, GF, (const s8v*)(lds + 32768), lane);

    float sm = 0.f, ssq = 0.f;
    #pragma unroll
    for (int mb = 0; mb < 8; ++mb){
      #pragma unroll
      for (int r = 0; r < 4; ++r){ sm += acc[mb][r]; ssq += acc[mb][r]*acc[mb][r]; }
    }
    sm  += __shfl_xor(sm, 16);  sm  += __shfl_xor(sm, 32);
    ssq += __shfl_xor(ssq, 16); ssq += __shfl_xor(ssq, 32);
    float mean = sm * (1.f/128.f);
    float rstd = rsqrtf(ssq * (1.f/128.f) - mean*mean + 1e-5f);

    const float* erow = edge + e*128;
    #pragma unroll
    for (int mb = 0; mb < 8; ++mb){
      f4 ev  = *(const f4*)(erow + mb*16 + g*4);
      f4 gv  = *(const f4*)(g_bn + mb*16 + g*4);
      f4 bv2 = *(const f4*)(b_bn + mb*16 + g*4);
      f4 o;
      #pragma unroll
      for (int r = 0; r < 4; ++r){
        float x = ev[r] + (acc[mb][r] - mean)*rstd*gv[r] + bv2[r];
        o[r] = (x > 20.f) ? x : __logf(1.f + __expf(x));
      }
      *(f4*)(out + e*128 + mb*16 + g*4) = o;
    }
  }
}

// ---------------------------------------------------------------------------
// Fallback: r2 fused kernel (known-good), unchanged.
// ---------------------------------------------------------------------------
__global__ __launch_bounds__(256) void edge_fused(
    const float* __restrict__ edge, const float* __restrict__ nlen, const float* __restrict__ nang,
    const float* __restrict__ bq,   const float* __restrict__ bk2,  const float* __restrict__ bm2,
    const float* __restrict__ bc,
    const float* __restrict__ g_att, const float* __restrict__ b_att,
    const float* __restrict__ g_bn,  const float* __restrict__ b_bn,
    const short* __restrict__ wsm,  const float* __restrict__ wsb,
    float* __restrict__ out)
{
  __shared__ short smem[2*16384];
  const int lane = threadIdx.x & 63;
  const int wid  = threadIdx.x >> 6;
  int tile = blockIdx.x*4 + wid;
  if (tile > NTILES-1) tile = NTILES-1;
  const int g  = lane >> 4;
  const int er = lane & 15;
  const size_t e = (size_t)tile*16 + er;
  const float* erow = edge + e*128;

  stage_mat(wsm + 0*16384, smem, wid, lane);
  s8v BE[4];
  #pragma unroll
  for (int kk = 0; kk < 4; ++kk) BE[kk] = load_bfrag(erow + kk*32 + g*8);
  f4 acc[8], gm[8];
  s4v qb[8], ekb[8], emb[8], gateb[8];
  s8v S[4], BL[4], BA[4];
  #pragma unroll
  for (int mb = 0; mb < 8; ++mb){ f4 z = {0.f,0.f,0.f,0.f}; gm[mb] = z; }
  __syncthreads();

  stage_mat(wsm + 1*16384, smem + 16384, wid, lane);
  #pragma unroll
  for (int mb = 0; mb < 8; ++mb) acc[mb] = *(const f4*)(bq + mb*16 + g*4);
  mm8l(acc, BE, (const s8v*)smem, lane);
  #pragma unroll
  for (int mb = 0; mb < 8; ++mb){
    s4v t4; t4[0]=f2bf(acc[mb][0]); t4[1]=f2bf(acc[mb][1]); t4[2]=f2bf(acc[mb][2]); t4[3]=f2bf(acc[mb][3]);
    qb[mb] = t4;
  }
  __syncthreads();

  stage_mat(wsm + 2*16384, smem, wid, lane);
  #pragma unroll
  for (int mb = 0; mb < 8; ++mb){ f4 z = {0.f,0.f,0.f,0.f}; acc[mb] = z; }
  mm8l(acc, BE, (const s8v*)(smem + 16384), lane);
  #pragma unroll
  for (int mb = 0; mb < 8; ++mb){
    s4v t4; t4[0]=f2bf(acc[mb][0]); t4[1]=f2bf(acc[mb][1]); t4[2]=f2bf(acc[mb][2]); t4[3]=f2bf(acc[mb][3]);
    ekb[mb] = t4;
  }
  __syncthreads();

  stage_mat(wsm + 8*16384, smem + 16384, wid, lane);
  #pragma unroll
  for (int mb = 0; mb < 8; ++mb){ f4 z = {0.f,0.f,0.f,0.f}; acc[mb] = z; }
  mm8l(acc, BE, (const s8v*)smem, lane);
  #pragma unroll
  for (int mb = 0; mb < 8; ++mb){
    s4v t4; t4[0]=f2bf(acc[mb][0]); t4[1]=f2bf(acc[mb][1]); t4[2]=f2bf(acc[mb][2]); t4[3]=f2bf(acc[mb][3]);
    emb[mb] = t4;
  }
  {
    const float* lrow = nlen + e*3*128;
    const float* arow = nang + e*3*128;
    #pragma unroll
    for (int kk = 0; kk < 4; ++kk){
      BL[kk] = load_bfrag(lrow + kk*32 + g*8);
      BA[kk] = load_bfrag(arow + kk*32 + g*8);
    }
  }
  __syncthreads();

  int cur = 1;
  #pragma unroll 1
  for (int t = 0; t < 3; ++t){
    stage_mat(wsm + 3*16384, smem + (cur^1)*16384, wid, lane);
    #pragma unroll
    for (int mb = 0; mb < 8; ++mb){
      f4 b = *(const f4*)(wsb + t*128 + mb*16 + g*4);
      #pragma unroll
      for (int r = 0; r < 4; ++r) b[r] += bf2f(ekb[mb][r]);
      acc[mb] = b;
    }
    mm8l(acc, BL, (const s8v*)(smem + cur*16384), lane);
    __syncthreads(); cur ^= 1;

    stage_mat(wsm + 5*16384, smem + (cur^1)*16384, wid, lane);
    mm8l(acc, BA, (const s8v*)(smem + cur*16384), lane);
    #pragma unroll
    for (int kk = 0; kk < 4; ++kk){
      #pragma unroll
      for (int p = 0; p < 4; ++p){
        float x0 = acc[2*kk][p];   S[kk][p]   = f2bf(x0 * sigm(x0));
        float x1 = acc[2*kk+1][p]; S[kk][4+p] = f2bf(x1 * sigm(x1));
      }
    }
    __syncthreads(); cur ^= 1;

    stage_mat(wsm + (size_t)(11+t)*16384, smem + (cur^1)*16384, wid, lane);
    #pragma unroll
    for (int mb = 0; mb < 8; ++mb) acc[mb] = *(const f4*)(bk2 + mb*16 + g*4);
    mm8l(acc, S, (const s8v*)(smem + cur*16384), lane);
    {
      float sm = 0.f, ssq = 0.f;
      #pragma unroll
      for (int mb = 0; mb < 8; ++mb){
        #pragma unroll
        for (int r = 0; r < 4; ++r){
          float a = bf2f(qb[mb][r]) * acc[mb][r] * 0.08838834764831845f;
          acc[mb][r] = a; sm += a; ssq += a*a;
        }
      }
      sm  += __shfl_xor(sm, 16);  sm  += __shfl_xor(sm, 32);
      ssq += __shfl_xor(ssq, 16); ssq += __shfl_xor(ssq, 32);
      float mean = sm * (1.f/128.f);
      float rstd = rsqrtf(ssq * (1.f/128.f) - mean*mean + 1e-5f);
      #pragma unroll
      for (int mb = 0; mb < 8; ++mb){
        f4 ga = *(const f4*)(g_att + mb*16 + g*4);
        f4 bb = *(const f4*)(b_att + mb*16 + g*4);
        s4v t4;
        #pragma unroll
        for (int r = 0; r < 4; ++r)
          t4[r] = f2bf(sigm((acc[mb][r] - mean)*rstd*ga[r] + bb[r]));
        gateb[mb] = t4;
      }
    }
    __syncthreads(); cur ^= 1;

    stage_mat(wsm + 4*16384, smem + (cur^1)*16384, wid, lane);
    #pragma unroll
    for (int mb = 0; mb < 8; ++mb){
      f4 b = *(const f4*)(wsb + 384 + t*128 + mb*16 + g*4);
      #pragma unroll
      for (int r = 0; r < 4; ++r) b[r] += bf2f(emb[mb][r]);
      acc[mb] = b;
    }
    mm8l(acc, BL, (const s8v*)(smem + cur*16384), lane);
    __syncthreads(); cur ^= 1;

    stage_mat(wsm + 6*16384, smem + (cur^1)*16384, wid, lane);
    mm8l(acc, BA, (const s8v*)(smem + cur*16384), lane);
    #pragma unroll
    for (int kk = 0; kk < 4; ++kk){
      #pragma unroll
      for (int p = 0; p < 4; ++p){
        float x0 = acc[2*kk][p];   S[kk][p]   = f2bf(x0 * sigm(x0));
        float x1 = acc[2*kk+1][p]; S[kk][4+p] = f2bf(x1 * sigm(x1));
      }
    }
    __syncthreads(); cur ^= 1;

    stage_mat(wsm + (size_t)(t < 2 ? 9 + t : 7)*16384, smem + (cur^1)*16384, wid, lane);
    #pragma unroll
    for (int mb = 0; mb < 8; ++mb) acc[mb] = *(const f4*)(bm2 + mb*16 + g*4);
    mm8l(acc, S, (const s8v*)(smem + cur*16384), lane);
    if (t < 2){
      const float* lrow = nlen + (e*3 + t + 1)*128;
      const float* arow = nang + (e*3 + t + 1)*128;
      #pragma unroll
      for (int kk = 0; kk < 4; ++kk){
        BL[kk] = load_bfrag(lrow + kk*32 + g*8);
        BA[kk] = load_bfrag(arow + kk*32 + g*8);
      }
    }
    #pragma unroll
    for (int mb = 0; mb < 8; ++mb){
      #pragma unroll
      for (int r = 0; r < 4; ++r) gm[mb][r] += acc[mb][r] * bf2f(gateb[mb][r]);
    }
    __syncthreads(); cur ^= 1;
  }

  s8v GF[4];
  #pragma unroll
  for (int kk = 0; kk < 4; ++kk){
    #pragma unroll
    for (int p = 0; p < 4; ++p){
      GF[kk][p]   = f2bf(gm[2*kk][p]);
      GF[kk][4+p] = f2bf(gm[2*kk+1][p]);
    }
  }
  #pragma unroll
  for (int mb = 0; mb < 8; ++mb){
    f4 b = *(const f4*)(bc + mb*16 + g*4);
    #pragma unroll
    for (int r = 0; r < 4; ++r) b[r] *= 3.f;
    acc[mb] = b;
  }
  mm8l(acc, GF, (const s8v*)(smem + cur*16384), lane);

  float sm = 0.f, ssq = 0.f;
  #pragma unroll
  for (int mb = 0; mb < 8; ++mb){
    #pragma unroll
    for (int r = 0; r < 4; ++r){ sm += acc[mb][r]; ssq += acc[mb][r]*acc[mb][r]; }
  }
  sm  += __shfl_xor(sm, 16);  sm  += __shfl_xor(sm, 32);
  ssq += __shfl_xor(ssq, 16); ssq += __shfl_xor(ssq, 32);
  float mean = sm * (1.f/128.f);
  float rstd = rsqrtf(ssq * (1.f/128.f) - mean*mean + 1e-5f);

  #pragma unroll
  for (int mb = 0; mb < 8; ++mb){
    f4 ev  = *(const f4*)(erow + mb*16 + g*4);
    f4 gv  = *(const f4*)(g_bn + mb*16 + g*4);
    f4 bv2 = *(const f4*)(b_bn + mb*16 + g*4);
    f4 o;
    #pragma unroll
    for (int r = 0; r < 4; ++r){
      float x = ev[r] + (acc[mb][r] - mean)*rstd*gv[r] + bv2[r];
      o[r] = (x > 20.f) ? x : log1pf(__expf(x));
    }
    *(f4*)(out + e*128 + mb*16 + g*4) = o;
  }
}

extern "C" void kernel_launch(void* const* d_in, const int* in_sizes, int n_in,
                              void* d_out, int out_size, void* d_ws, size_t ws_size,
                              hipStream_t stream)
{
  const float* edge = (const float*)d_in[0];
  const float* nlen = (const float*)d_in[1];
  const float* nang = (const float*)d_in[2];
  const float* Wq  = (const float*)d_in[3];
  const float* bq  = (const float*)d_in[4];
  const float* Wk  = (const float*)d_in[5];
  const float* bk  = (const float*)d_in[6];
  const float* Wv  = (const float*)d_in[7];
  const float* bv  = (const float*)d_in[8];
  const float* Wke = (const float*)d_in[9];
  const float* bke = (const float*)d_in[10];
  const float* Wve = (const float*)d_in[11];
  const float* bve = (const float*)d_in[12];
  const float* We  = (const float*)d_in[13];
  const float* Wc  = (const float*)d_in[14];
  const float* bc  = (const float*)d_in[15];
  const float* Wk1 = (const float*)d_in[16];
  const float* bk1 = (const float*)d_in[17];
  const float* Wk2 = (const float*)d_in[18];
  const float* bk2 = (const float*)d_in[19];
  const float* Wm1 = (const float*)d_in[20];
  const float* bm1 = (const float*)d_in[21];
  const float* Wm2 = (const float*)d_in[22];
  const float* bm2 = (const float*)d_in[23];
  const float* g_att = (const float*)d_in[24];
  const float* b_att = (const float*)d_in[25];
  const float* g_bn  = (const float*)d_in[26];
  const float* b_bn  = (const float*)d_in[27];

  short* wsm = (short*)d_ws;
  float* wsb = (float*)((char*)d_ws + OFF_WSB);
  char*  ws  = (char*)d_ws;

  pack_weights<<<dim3(14*64), dim3(256), 0, stream>>>(
      Wq, Wk, Wv, Wke, Wve, We, Wc, Wk1, Wk2, Wm1, Wm2, wsm);
  make_biases<<<dim3(6), dim3(128), 0, stream>>>(
      bk, bke, bk1, bv, bve, bm1, Wk1, Wm1, wsb);

  if (ws_size >= WS_NEED){
    proj<<<dim3(256), dim3(256), 0, stream>>>(edge, bq, wsm, ws);
    hpass<<<dim3(85, 3), dim3(512), 0, stream>>>(nlen, nang, wsm, wsb, ws);
    gfin<<<dim3(256), dim3(256), 0, stream>>>(
        edge, bk2, bm2, bc, g_att, b_att, g_bn, b_bn, wsm, ws, (float*)d_out);
  } else {
    edge_fused<<<dim3((NTILES + 3)/4), dim3(256), 0, stream>>>(
        edge, nlen, nang, bq, bk2, bm2, bc, g_att, b_att, g_bn, b_bn,
        wsm, wsb, (float*)d_out);
  }
}